// Round 1
// baseline (817.482 us; speedup 1.0000x reference)
//
#include <hip/hip_runtime.h>
#include <math.h>

#define NN 256
#define NPIX 65536
#define NFIELD 81
#define NF2 41
#define NPAIR 801
#define PTILE 64
#define NTILE 13
#define NPAIR_PAD (NTILE*PTILE)   // 832
#define KSPLIT 32
#define KCH 64
#define EPSF 1e-8f

// ---------------- FFT helpers (256-point, LDS-resident) ----------------
// DIF: natural order in -> bit-reversed out.  DIT: bit-reversed in -> natural out.
// Composition DIF(inverse) -> pointwise -> DIT(forward) needs no explicit reversal.

__device__ inline void make_tw(float* twc, float* tws, int tid, int nthr) {
    for (int i = tid; i < 128; i += nthr) {
        float ang = (float)i * (6.283185307179586f / 256.0f);
        twc[i] = cosf(ang);
        tws[i] = sinf(ang);
    }
}

template<int T>
__device__ inline void dif_fft(float2* row, const float* twc, const float* tws,
                               float sgn, int lane) {
    #pragma unroll
    for (int s = 0; s < 8; ++s) {
        int half = 128 >> s;
        __syncthreads();
        #pragma unroll
        for (int bi = 0; bi < 128 / T; ++bi) {
            int b = lane + bi * T;
            int t = b & (half - 1);
            int blk = b >> (7 - s);
            int p0 = (blk << (8 - s)) + t;
            float2 u = row[p0];
            float2 v = row[p0 + half];
            row[p0] = make_float2(u.x + v.x, u.y + v.y);
            float dx = u.x - v.x, dy = u.y - v.y;
            int w = t << s;
            float c = twc[w], si = sgn * tws[w];
            row[p0 + half] = make_float2(dx * c - dy * si, dx * si + dy * c);
        }
    }
    __syncthreads();
}

template<int T>
__device__ inline void dit_fft(float2* row, const float* twc, const float* tws,
                               float sgn, int lane) {
    #pragma unroll
    for (int s = 0; s < 8; ++s) {
        int half = 1 << s;
        __syncthreads();
        #pragma unroll
        for (int bi = 0; bi < 128 / T; ++bi) {
            int b = lane + bi * T;
            int t = b & (half - 1);
            int blk = b >> s;
            int p0 = (blk << (s + 1)) + t;
            int w = t << (7 - s);
            float c = twc[w], si = sgn * tws[w];
            float2 v = row[p0 + half];
            float vx = v.x * c - v.y * si;
            float vy = v.x * si + v.y * c;
            float2 u = row[p0];
            row[p0] = make_float2(u.x + vx, u.y + vy);
            row[p0 + half] = make_float2(u.x - vx, u.y - vy);
        }
    }
    __syncthreads();
}

// ---------------- K0: psi2 = r^2 + i^2 ----------------
__global__ void k0_psi2(const float4* __restrict__ r, const float4* __restrict__ im,
                        float4* __restrict__ out, int n4) {
    int i = blockIdx.x * blockDim.x + threadIdx.x;
    if (i < n4) {
        float4 a = r[i], b = im[i];
        out[i] = make_float4(a.x * a.x + b.x * b.x, a.y * a.y + b.y * b.y,
                             a.z * a.z + b.z * b.z, a.w * a.w + b.w * b.w);
    }
}

// ---------------- K1: rows -> product with psi, inverse DIF over x ----------------
__global__ void k1_rowifft(const float* __restrict__ xhat,
                           const float* __restrict__ psiR,
                           const float* __restrict__ psiI,
                           float2* __restrict__ P) {
    __shared__ float2 buf[4][257];
    __shared__ float twc[128], tws[128];
    int tid = threadIdx.x;
    make_tw(twc, tws, tid, 256);
    int fi = tid >> 6, lane = tid & 63;
    int f = blockIdx.y;
    int y = blockIdx.x * 4 + fi;
    const float inv = 1.0f / 256.0f;
    size_t rb = (size_t)f * NPIX + (size_t)y * NN;
    for (int j = lane; j < NN; j += 64) {
        float xr = xhat[(y * NN + j) * 2 + 0];
        float xi = xhat[(y * NN + j) * 2 + 1];
        float pr = psiR[rb + j], pi = psiI[rb + j];
        buf[fi][j] = make_float2((xr * pr - xi * pi) * inv, (xr * pi + xi * pr) * inv);
    }
    dif_fft<64>(&buf[fi][0], twc, tws, +1.0f, lane);
    for (int j = lane; j < NN; j += 64) P[rb + j] = buf[fi][j];
}

// ---------------- K2: per column: inverse DIF over y, modulus, forward DIT over y ----------------
__global__ void k2_colpass(float2* __restrict__ P) {
    __shared__ float2 buf[16][257];
    __shared__ float twc[128], tws[128];
    int tid = threadIdx.x;      // 256 threads: 16 columns x 16 threads
    make_tw(twc, tws, tid, 256);
    int c = tid & 15, tl = tid >> 4;
    int f = blockIdx.y;
    int xb = blockIdx.x * 16;
    size_t fb = (size_t)f * NPIX;
    #pragma unroll
    for (int i = 0; i < 16; ++i) {
        int y = tl + i * 16;
        buf[c][y] = P[fb + (size_t)y * NN + xb + c];
    }
    dif_fft<16>(&buf[c][0], twc, tws, +1.0f, tl);
    const float inv = 1.0f / 256.0f;
    #pragma unroll
    for (int i = 0; i < 16; ++i) {
        int p = tl + i * 16;
        float2 v = buf[c][p];
        float vx = v.x * inv, vy = v.y * inv;
        buf[c][p] = make_float2(sqrtf(vx * vx + vy * vy + EPSF), 0.0f);
    }
    dit_fft<16>(&buf[c][0], twc, tws, -1.0f, tl);
    #pragma unroll
    for (int i = 0; i < 16; ++i) {
        int y = tl + i * 16;
        P[fb + (size_t)y * NN + xb + c] = buf[c][y];
    }
}

// ---------------- K3: rows -> forward DIT over x (consumes bitrev-x) ----------------
__global__ void k3_rowfft(float2* __restrict__ P) {
    __shared__ float2 buf[4][257];
    __shared__ float twc[128], tws[128];
    int tid = threadIdx.x;
    make_tw(twc, tws, tid, 256);
    int fi = tid >> 6, lane = tid & 63;
    int f = blockIdx.y;
    int y = blockIdx.x * 4 + fi;
    size_t rb = (size_t)f * NPIX + (size_t)y * NN;
    for (int j = lane; j < NN; j += 64) buf[fi][j] = P[rb + j];
    dit_fft<64>(&buf[fi][0], twc, tws, -1.0f, lane);
    for (int j = lane; j < NN; j += 64) P[rb + j] = buf[fi][j];
}

// ---------------- pair enumeration (closed form) ----------------
__device__ __host__ inline int fsj(int j) { int t = j >> 1; return (t > 4 ? 4 : t) * 8; }

__device__ inline void pair_uv(int p, int& u, int& v) {
    if (p < 360) {                     // M: j*36 + tri(a,b), b>=a
        int j = p / 36, r = p % 36;
        int a = 0;
        while (r >= 8 - a) { r -= 8 - a; ++a; }
        int b = a + r;
        u = a * 10 + j; v = b * 10 + j;
    } else if (p < 720) {              // N: 360 + 4l(l-1) + i*l + j  (j<l)
        int q = p - 360;
        int l = 1;
        while (4 * (l + 1) * l <= q) ++l;
        int rem = q - 4 * l * (l - 1);
        int i = rem / l, j = rem % l;
        u = i * 10 + j; v = i * 10 + l;
    } else if (p < 800) {              // A: 720 + i*10 + j, vs a_hat
        int q = p - 720;
        u = (q / 10) * 10 + (q % 10); v = 80;
    } else {                           // s0 (p==800) and pad
        u = 80; v = 80;
    }
}

__device__ inline int pair_fstart(int p) {
    if (p < 360) return fsj(p / 36);
    if (p < 720) {
        int q = p - 360;
        int l = 1;
        while (4 * (l + 1) * l <= q) ++l;
        return fsj(l);
    }
    if (p < 800) return 32;
    if (p == 800) return 40;
    return 41;
}

// ---------------- C1: Out[f,p] = sum_xy psi2[f]*P[u]*conj(P[v]), split-K ----------------
__global__ void __launch_bounds__(256) c1_contract(const float2* __restrict__ P,
                                                   const float* __restrict__ psi2,
                                                   float* __restrict__ Mpart) {
    __shared__ float psil[NF2 * 65];
    __shared__ float2 cl[PTILE * 65];
    __shared__ int su[PTILE], sv[PTILE];
    __shared__ int sm0;
    int tid = threadIdx.x;
    int split = blockIdx.x, tile = blockIdx.y;
    int pbase = tile * PTILE;
    if (tid < PTILE) {
        int u, v;
        pair_uv(pbase + tid, u, v);
        su[tid] = u; sv[tid] = v;
    }
    if (tid == 0) {
        int fmin = 41;
        for (int q = 0; q < PTILE; ++q) {
            int fs = pair_fstart(pbase + q);
            if (fs < fmin) fmin = fs;
        }
        sm0 = fmin >> 3;   // skip whole f-octaves below fmin
    }
    __syncthreads();
    int m0 = sm0;
    int fa = tid & 7, pb = tid >> 3;
    int w = tid >> 6, lane = tid & 63;
    float2 acc[6][2];
    #pragma unroll
    for (int m = 0; m < 6; ++m) {
        acc[m][0] = make_float2(0.f, 0.f);
        acc[m][1] = make_float2(0.f, 0.f);
    }
    for (int ch = 0; ch < (NPIX / KSPLIT) / KCH; ++ch) {
        int base = split * (NPIX / KSPLIT) + ch * KCH;
        for (int idx = tid; idx < NF2 * KCH; idx += 256) {
            int ff = idx >> 6, kk = idx & 63;
            psil[ff * 65 + kk] = psi2[(size_t)ff * NPIX + base + kk];
        }
        for (int pi = w; pi < PTILE; pi += 4) {
            float2 A = P[(size_t)su[pi] * NPIX + base + lane];
            float2 B = P[(size_t)sv[pi] * NPIX + base + lane];
            cl[pi * 65 + lane] = make_float2(A.x * B.x + A.y * B.y,
                                             A.y * B.x - A.x * B.y);
        }
        __syncthreads();
        for (int k = 0; k < KCH; ++k) {
            float2 c0 = cl[pb * 65 + k];
            float2 c1 = cl[(pb + 32) * 65 + k];
            #pragma unroll
            for (int m = 0; m < 6; ++m) {
                int f = fa + 8 * m;
                if (m >= m0 && f < NF2) {
                    float a = psil[f * 65 + k];
                    acc[m][0].x += a * c0.x; acc[m][0].y += a * c0.y;
                    acc[m][1].x += a * c1.x; acc[m][1].y += a * c1.y;
                }
            }
        }
        __syncthreads();
    }
    float* out = Mpart + (size_t)split * (NF2 * NPAIR_PAD * 2);
    #pragma unroll
    for (int m = 0; m < 6; ++m) {
        int f = fa + 8 * m;
        if (f < NF2) {
            int p0 = pbase + pb, p1 = pbase + pb + 32;
            out[((size_t)f * NPAIR_PAD + p0) * 2 + 0] = acc[m][0].x;
            out[((size_t)f * NPAIR_PAD + p0) * 2 + 1] = acc[m][0].y;
            out[((size_t)f * NPAIR_PAD + p1) * 2 + 0] = acc[m][1].x;
            out[((size_t)f * NPAIR_PAD + p1) * 2 + 1] = acc[m][1].y;
        }
    }
}

// ---------------- C1b: reduce split-K partials ----------------
__global__ void c1b_reduce(const float* __restrict__ Mpart, float* __restrict__ Mout) {
    int idx = blockIdx.x * 256 + threadIdx.x;
    if (idx < NF2 * NPAIR_PAD * 2) {
        float s = 0.f;
        for (int sp = 0; sp < KSPLIT; ++sp)
            s += Mpart[(size_t)sp * (NF2 * NPAIR_PAD * 2) + idx];
        Mout[idx] = s;
    }
}

// ---------------- C2: magnitude + assembly in reference output order ----------------
__device__ inline int seglen_d(int j, int i) {
    int s = (NF2 - fsj(j)) * (8 - i) + 9;
    for (int l = j + 1; l < 10; ++l) s += NF2 - fsj(l);
    return s;
}

__device__ inline float magof(const float* Mout, int f, int p) {
    const float nrm = 1.0f / 65536.0f;
    float re = Mout[((size_t)f * NPAIR_PAD + p) * 2 + 0] * nrm;
    float im = Mout[((size_t)f * NPAIR_PAD + p) * 2 + 1] * nrm;
    return sqrtf(re * re + im * im + EPSF);
}

__global__ void c2_assemble(const float* __restrict__ Mout, float* __restrict__ out) {
    int bid = blockIdx.x, tid = threadIdx.x;
    if (bid == 0) {
        if (tid == 0) out[0] = magof(Mout, 40, 800);   // s0
        return;
    }
    int idx = bid - 1;
    int j = idx / 8, i = idx % 8;
    int base = 1;
    for (int q = 0; q < idx; ++q) base += seglen_d(q / 8, q % 8);
    int fs = fsj(j);
    int d = 8 - i;
    int len1 = (NF2 - fs) * d;
    int total = seglen_d(j, i);
    for (int e = tid; e < total; e += 256) {
        int f, p;
        if (e < len1) {
            f = fs + e / d;
            int b = i + e % d;
            p = j * 36 + (i * 8 - i * (i - 1) / 2 + (b - i));
        } else {
            int e2 = e - len1;
            bool found = false;
            f = 0; p = 0;
            for (int l = j + 1; l < 10; ++l) {
                int ll = NF2 - fsj(l);
                if (e2 < ll) {
                    f = fsj(l) + e2;
                    p = 360 + 4 * l * (l - 1) + i * l + j;
                    found = true;
                    break;
                }
                e2 -= ll;
            }
            if (!found) { f = 32 + e2; p = 720 + i * 10 + j; }
        }
        out[base + e] = magof(Mout, f, p);
    }
}

// ---------------- launch ----------------
extern "C" void kernel_launch(void* const* d_in, const int* in_sizes, int n_in,
                              void* d_out, int out_size, void* d_ws, size_t ws_size,
                              hipStream_t stream) {
    const float* xhat  = (const float*)d_in[0];
    const float* psiR  = (const float*)d_in[1];
    const float* psiI  = (const float*)d_in[2];
    const float* p2R   = (const float*)d_in[3];
    const float* p2I   = (const float*)d_in[4];

    char* ws = (char*)d_ws;
    float2* P = (float2*)ws;
    size_t off = (size_t)NFIELD * NPIX * sizeof(float2);
    float* psi2 = (float*)(ws + off);
    off += (size_t)NF2 * NPIX * sizeof(float);
    float* Mpart = (float*)(ws + off);
    off += (size_t)KSPLIT * NF2 * NPAIR_PAD * 2 * sizeof(float);
    float* Mout = (float*)(ws + off);

    int n4 = NF2 * NPIX / 4;
    k0_psi2<<<dim3((n4 + 255) / 256), dim3(256), 0, stream>>>(
        (const float4*)p2R, (const float4*)p2I, (float4*)psi2, n4);
    k1_rowifft<<<dim3(64, NFIELD), dim3(256), 0, stream>>>(xhat, psiR, psiI, P);
    k2_colpass<<<dim3(16, NFIELD), dim3(256), 0, stream>>>(P);
    k3_rowfft<<<dim3(64, NFIELD), dim3(256), 0, stream>>>(P);
    c1_contract<<<dim3(KSPLIT, NTILE), dim3(256), 0, stream>>>(P, psi2, Mpart);
    c1b_reduce<<<dim3((NF2 * NPAIR_PAD * 2 + 255) / 256), dim3(256), 0, stream>>>(Mpart, Mout);
    c2_assemble<<<dim3(81), dim3(256), 0, stream>>>(Mout, (float*)d_out);
}

// Round 2
// 589.251 us; speedup vs baseline: 1.3873x; 1.3873x over previous
//
#include <hip/hip_runtime.h>
#include <math.h>

#define NN 256
#define NPIX 65536
#define NFIELD 81
#define NF2 41
#define FPAD 44              // f padded to 11 quads
#define PTILE 64
#define NTILE 13
#define NPAIR_PAD (NTILE*PTILE)   // 832
#define KSPLIT 128
#define KPB (NPIX / KSPLIT)       // 512 k per split
#define KCH 32
#define NCHUNK (KPB / KCH)        // 16
#define EPSF 1e-8f

// ---------------- FFT helpers (256-point, LDS-resident) ----------------
// DIF: natural order in -> bit-reversed out.  DIT: bit-reversed in -> natural out.
// Composition DIF(inverse) -> pointwise -> DIT(forward) needs no explicit reversal.

__device__ inline void make_tw(float* twc, float* tws, int tid, int nthr) {
    for (int i = tid; i < 128; i += nthr) {
        float ang = (float)i * (6.283185307179586f / 256.0f);
        twc[i] = cosf(ang);
        tws[i] = sinf(ang);
    }
}

template<int T>
__device__ inline void dif_fft(float2* row, const float* twc, const float* tws,
                               float sgn, int lane) {
    #pragma unroll
    for (int s = 0; s < 8; ++s) {
        int half = 128 >> s;
        __syncthreads();
        #pragma unroll
        for (int bi = 0; bi < 128 / T; ++bi) {
            int b = lane + bi * T;
            int t = b & (half - 1);
            int blk = b >> (7 - s);
            int p0 = (blk << (8 - s)) + t;
            float2 u = row[p0];
            float2 v = row[p0 + half];
            row[p0] = make_float2(u.x + v.x, u.y + v.y);
            float dx = u.x - v.x, dy = u.y - v.y;
            int w = t << s;
            float c = twc[w], si = sgn * tws[w];
            row[p0 + half] = make_float2(dx * c - dy * si, dx * si + dy * c);
        }
    }
    __syncthreads();
}

template<int T>
__device__ inline void dit_fft(float2* row, const float* twc, const float* tws,
                               float sgn, int lane) {
    #pragma unroll
    for (int s = 0; s < 8; ++s) {
        int half = 1 << s;
        __syncthreads();
        #pragma unroll
        for (int bi = 0; bi < 128 / T; ++bi) {
            int b = lane + bi * T;
            int t = b & (half - 1);
            int blk = b >> s;
            int p0 = (blk << (s + 1)) + t;
            int w = t << (7 - s);
            float c = twc[w], si = sgn * tws[w];
            float2 v = row[p0 + half];
            float vx = v.x * c - v.y * si;
            float vy = v.x * si + v.y * c;
            float2 u = row[p0];
            row[p0] = make_float2(u.x + vx, u.y + vy);
            row[p0 + half] = make_float2(u.x - vx, u.y - vy);
        }
    }
    __syncthreads();
}

// ---------------- K0: psi2 = r^2 + i^2 ----------------
__global__ void k0_psi2(const float4* __restrict__ r, const float4* __restrict__ im,
                        float4* __restrict__ out, int n4) {
    int i = blockIdx.x * blockDim.x + threadIdx.x;
    if (i < n4) {
        float4 a = r[i], b = im[i];
        out[i] = make_float4(a.x * a.x + b.x * b.x, a.y * a.y + b.y * b.y,
                             a.z * a.z + b.z * b.z, a.w * a.w + b.w * b.w);
    }
}

// ---------------- K1: rows -> product with psi, inverse DIF over x ----------------
__global__ void k1_rowifft(const float* __restrict__ xhat,
                           const float* __restrict__ psiR,
                           const float* __restrict__ psiI,
                           float2* __restrict__ P) {
    __shared__ float2 buf[4][257];
    __shared__ float twc[128], tws[128];
    int tid = threadIdx.x;
    make_tw(twc, tws, tid, 256);
    int fi = tid >> 6, lane = tid & 63;
    int f = blockIdx.y;
    int y = blockIdx.x * 4 + fi;
    const float inv = 1.0f / 256.0f;
    size_t rb = (size_t)f * NPIX + (size_t)y * NN;
    for (int j = lane; j < NN; j += 64) {
        float xr = xhat[(y * NN + j) * 2 + 0];
        float xi = xhat[(y * NN + j) * 2 + 1];
        float pr = psiR[rb + j], pi = psiI[rb + j];
        buf[fi][j] = make_float2((xr * pr - xi * pi) * inv, (xr * pi + xi * pr) * inv);
    }
    dif_fft<64>(&buf[fi][0], twc, tws, +1.0f, lane);
    for (int j = lane; j < NN; j += 64) P[rb + j] = buf[fi][j];
}

// ---------------- K2: per column: inverse DIF over y, modulus, forward DIT over y ----------------
__global__ void k2_colpass(float2* __restrict__ P) {
    __shared__ float2 buf[16][257];
    __shared__ float twc[128], tws[128];
    int tid = threadIdx.x;      // 256 threads: 16 columns x 16 threads
    make_tw(twc, tws, tid, 256);
    int c = tid & 15, tl = tid >> 4;
    int f = blockIdx.y;
    int xb = blockIdx.x * 16;
    size_t fb = (size_t)f * NPIX;
    #pragma unroll
    for (int i = 0; i < 16; ++i) {
        int y = tl + i * 16;
        buf[c][y] = P[fb + (size_t)y * NN + xb + c];
    }
    dif_fft<16>(&buf[c][0], twc, tws, +1.0f, tl);
    const float inv = 1.0f / 256.0f;
    #pragma unroll
    for (int i = 0; i < 16; ++i) {
        int p = tl + i * 16;
        float2 v = buf[c][p];
        float vx = v.x * inv, vy = v.y * inv;
        buf[c][p] = make_float2(sqrtf(vx * vx + vy * vy + EPSF), 0.0f);
    }
    dit_fft<16>(&buf[c][0], twc, tws, -1.0f, tl);
    #pragma unroll
    for (int i = 0; i < 16; ++i) {
        int y = tl + i * 16;
        P[fb + (size_t)y * NN + xb + c] = buf[c][y];
    }
}

// ---------------- K3: rows -> forward DIT over x (consumes bitrev-x) ----------------
__global__ void k3_rowfft(float2* __restrict__ P) {
    __shared__ float2 buf[4][257];
    __shared__ float twc[128], tws[128];
    int tid = threadIdx.x;
    make_tw(twc, tws, tid, 256);
    int fi = tid >> 6, lane = tid & 63;
    int f = blockIdx.y;
    int y = blockIdx.x * 4 + fi;
    size_t rb = (size_t)f * NPIX + (size_t)y * NN;
    for (int j = lane; j < NN; j += 64) buf[fi][j] = P[rb + j];
    dit_fft<64>(&buf[fi][0], twc, tws, -1.0f, lane);
    for (int j = lane; j < NN; j += 64) P[rb + j] = buf[fi][j];
}

// ---------------- pair enumeration, SORTED by f-start group ----------------
// group g covers pairs [G[g], G[g+1]) with fstart = 8*g.
// Within group g: M pairs j=2g (36, tri a<=b), M pairs j=2g+1 (36),
//                 N pairs l=2g (8*l, skipped for g=0), N pairs l=2g+1 (8*l),
//                 then (g==4 only) A pairs (80).  s==800: s0.  801..831: pad.
__device__ __host__ inline int fsj(int j) { int t = j >> 1; return (t > 4 ? 4 : t) * 8; }

__device__ inline int group_of(int s) {
    return (s < 80) ? 0 : (s < 192) ? 1 : (s < 336) ? 2 : (s < 512) ? 3 : 4;
}

__device__ inline void pair_sorted(int s, int& u, int& v) {
    if (s >= 800) { u = 80; v = 80; return; }   // s0 and pad
    const int Gs[5] = {0, 80, 192, 336, 512};
    int g = group_of(s);
    int r = s - Gs[g];
    if (r < 72) {                       // M section
        int j = 2 * g + (r >= 36);
        int rr = (r >= 36) ? r - 36 : r;
        int a = 0;
        while (rr >= 8 - a) { rr -= 8 - a; ++a; }
        int b = a + rr;
        u = a * 10 + j; v = b * 10 + j;
        return;
    }
    int r2 = r - 72;                    // N section
    int l0 = 2 * g;
    int c0 = (l0 >= 1) ? 8 * l0 : 0;
    if (r2 < c0) { int i = r2 / l0, j = r2 % l0; u = i * 10 + j; v = i * 10 + l0; return; }
    r2 -= c0;
    int l1 = 2 * g + 1;
    if (r2 < 8 * l1) { int i = r2 / l1, j = r2 % l1; u = i * 10 + j; v = i * 10 + l1; return; }
    r2 -= 8 * l1;                       // A section (g==4 only): r2 = i*10+j
    u = r2; v = 80;
}

// inverse maps (for c2): sorted index of each pair type
__device__ inline int pM(int a, int b, int j) {
    const int Gt[5] = {0, 80, 192, 336, 512};
    return Gt[j >> 1] + (j & 1) * 36 + a * 8 - a * (a - 1) / 2 + (b - a);
}
__device__ inline int pN(int i, int j, int l) {
    const int Gt[5] = {0, 80, 192, 336, 512};
    return Gt[l >> 1] + 72 + ((l & 1) ? 8 * (l - 1) : 0) + i * l + j;
}
// A pairs: 720 + i*10 + j ; s0: 800  (same as sorted layout)

// ---------------- C1: Mout[f,p] += sum_k psi2[f,k]*C[p,k], split-K + atomics ----------------
__global__ void __launch_bounds__(256) c1_contract(const float2* __restrict__ P,
                                                   const float* __restrict__ psi2,
                                                   float* __restrict__ Mout) {
    __shared__ float2 clc[KCH][66];      // [k][pair], rows 528B (16B-aligned quads)
    __shared__ float  psit[KCH][FPAD];   // [k][f], rows 176B
    __shared__ int su[PTILE], sv[PTILE];
    int tid = threadIdx.x;
    int split = blockIdx.x, tile = blockIdx.y;
    int pbase = tile * PTILE;
    if (tid < PTILE) {
        int u, v;
        pair_sorted(pbase + tid, u, v);
        su[tid] = u; sv[tid] = v;
    }
    int qs = 2 * group_of(pbase);        // first active f-quad of this tile
    int pg = tid & 15;                   // pair quad: pairs pbase + pg*4 .. +3
    int fq = tid >> 4;
    int quad = qs + fq;                  // f-quad: f = quad*4 .. +3
    bool active = quad <= 10;
    int kk = tid & 31, ph = tid >> 5;    // staging map
    float ar[4][4], ai[4][4];
    #pragma unroll
    for (int a = 0; a < 4; ++a)
        #pragma unroll
        for (int b = 0; b < 4; ++b) { ar[a][b] = 0.f; ai[a][b] = 0.f; }
    __syncthreads();

    for (int ch = 0; ch < NCHUNK; ++ch) {
        int base = split * KPB + ch * KCH;
        // stage psi_t[k][f] (zero-pad f>=41)
        #pragma unroll
        for (int t = 0; t < 6; ++t) {
            int f = ph + 8 * t;
            if (f < FPAD)
                psit[kk][f] = (f < NF2) ? psi2[(size_t)f * NPIX + base + kk] : 0.f;
        }
        // build C[k][p] = P[u]*conj(P[v])  (pairs stride 8 -> parity-split LDS banks)
        #pragma unroll
        for (int t = 0; t < 8; ++t) {
            int p = ph + 8 * t;
            float2 A = P[(size_t)su[p] * NPIX + base + kk];
            float2 B = P[(size_t)sv[p] * NPIX + base + kk];
            clc[kk][p] = make_float2(A.x * B.x + A.y * B.y, A.y * B.x - A.x * B.y);
        }
        __syncthreads();
        if (active) {
            #pragma unroll 4
            for (int k = 0; k < KCH; ++k) {
                float4 pq = *(const float4*)&psit[k][quad * 4];
                float4 c0 = *(const float4*)&clc[k][pg * 4];      // re0,im0,re1,im1
                float4 c1 = *(const float4*)&clc[k][pg * 4 + 2];  // re2,im2,re3,im3
                float cr[4] = {c0.x, c0.z, c1.x, c1.z};
                float ci[4] = {c0.y, c0.w, c1.y, c1.w};
                #pragma unroll
                for (int fi = 0; fi < 4; ++fi) {
                    float pv = (fi == 0) ? pq.x : (fi == 1) ? pq.y : (fi == 2) ? pq.z : pq.w;
                    #pragma unroll
                    for (int pj = 0; pj < 4; ++pj) {
                        ar[fi][pj] += pv * cr[pj];
                        ai[fi][pj] += pv * ci[pj];
                    }
                }
            }
        }
        __syncthreads();
    }
    if (active) {
        #pragma unroll
        for (int fi = 0; fi < 4; ++fi) {
            int f = quad * 4 + fi;
            #pragma unroll
            for (int pj = 0; pj < 4; ++pj) {
                int p = pbase + pg * 4 + pj;
                atomicAdd(&Mout[((size_t)f * NPAIR_PAD + p) * 2 + 0], ar[fi][pj]);
                atomicAdd(&Mout[((size_t)f * NPAIR_PAD + p) * 2 + 1], ai[fi][pj]);
            }
        }
    }
}

// ---------------- C2: magnitude + assembly in reference output order ----------------
__device__ inline int seglen_d(int j, int i) {
    int s = (NF2 - fsj(j)) * (8 - i) + 9;
    for (int l = j + 1; l < 10; ++l) s += NF2 - fsj(l);
    return s;
}

__device__ inline float magof(const float* Mout, int f, int p) {
    const float nrm = 1.0f / 65536.0f;
    float re = Mout[((size_t)f * NPAIR_PAD + p) * 2 + 0] * nrm;
    float im = Mout[((size_t)f * NPAIR_PAD + p) * 2 + 1] * nrm;
    return sqrtf(re * re + im * im + EPSF);
}

__global__ void c2_assemble(const float* __restrict__ Mout, float* __restrict__ out) {
    int bid = blockIdx.x, tid = threadIdx.x;
    if (bid == 0) {
        if (tid == 0) out[0] = magof(Mout, 40, 800);   // s0
        return;
    }
    int idx = bid - 1;
    int j = idx / 8, i = idx % 8;
    int base = 1;
    for (int q = 0; q < idx; ++q) base += seglen_d(q / 8, q % 8);
    int fs = fsj(j);
    int d = 8 - i;
    int len1 = (NF2 - fs) * d;
    int total = seglen_d(j, i);
    for (int e = tid; e < total; e += 256) {
        int f, p;
        if (e < len1) {
            f = fs + e / d;
            int b = i + e % d;
            p = pM(i, b, j);
        } else {
            int e2 = e - len1;
            bool found = false;
            f = 0; p = 0;
            for (int l = j + 1; l < 10; ++l) {
                int ll = NF2 - fsj(l);
                if (e2 < ll) {
                    f = fsj(l) + e2;
                    p = pN(i, j, l);
                    found = true;
                    break;
                }
                e2 -= ll;
            }
            if (!found) { f = 32 + e2; p = 720 + i * 10 + j; }
        }
        out[base + e] = magof(Mout, f, p);
    }
}

// ---------------- launch ----------------
extern "C" void kernel_launch(void* const* d_in, const int* in_sizes, int n_in,
                              void* d_out, int out_size, void* d_ws, size_t ws_size,
                              hipStream_t stream) {
    const float* xhat  = (const float*)d_in[0];
    const float* psiR  = (const float*)d_in[1];
    const float* psiI  = (const float*)d_in[2];
    const float* p2R   = (const float*)d_in[3];
    const float* p2I   = (const float*)d_in[4];

    char* ws = (char*)d_ws;
    float2* P = (float2*)ws;
    size_t off = (size_t)NFIELD * NPIX * sizeof(float2);
    float* psi2 = (float*)(ws + off);
    off += (size_t)NF2 * NPIX * sizeof(float);
    float* Mout = (float*)(ws + off);
    size_t mout_bytes = (size_t)FPAD * NPAIR_PAD * 2 * sizeof(float);

    hipMemsetAsync(Mout, 0, mout_bytes, stream);

    int n4 = NF2 * NPIX / 4;
    k0_psi2<<<dim3((n4 + 255) / 256), dim3(256), 0, stream>>>(
        (const float4*)p2R, (const float4*)p2I, (float4*)psi2, n4);
    k1_rowifft<<<dim3(64, NFIELD), dim3(256), 0, stream>>>(xhat, psiR, psiI, P);
    k2_colpass<<<dim3(16, NFIELD), dim3(256), 0, stream>>>(P);
    k3_rowfft<<<dim3(64, NFIELD), dim3(256), 0, stream>>>(P);
    c1_contract<<<dim3(KSPLIT, NTILE), dim3(256), 0, stream>>>(P, psi2, Mout);
    c2_assemble<<<dim3(81), dim3(256), 0, stream>>>(Mout, (float*)d_out);
}